// Round 2
// baseline (333.595 us; speedup 1.0000x reference)
//
#include <hip/hip_runtime.h>

#define N_NODES 100000
#define IN_F 256
#define OUT_F 128
#define SCAN_ELEMS 1024
#define EDGE_ILP 8
#define NXCD 8

typedef float f32x4 __attribute__((ext_vector_type(4)));
typedef __bf16 bf16x8 __attribute__((ext_vector_type(8)));

// RNE pack of two fp32 -> packed bf16x2
__device__ inline unsigned cvt2_bf16(float a, float b) {
  unsigned ua = __float_as_uint(a), ub = __float_as_uint(b);
  ua = (ua + 0x7fffu + ((ua >> 16) & 1u)) >> 16;
  ub = (ub + 0x7fffu + ((ub >> 16) & 1u)) >> 16;
  return ua | (ub << 16);
}
__device__ inline unsigned short cvt1_bf16(float a) {
  unsigned ua = __float_as_uint(a);
  return (unsigned short)((ua + 0x7fffu + ((ua >> 16) & 1u)) >> 16);
}

// HW_REG_XCC_ID = hwreg 20, offset 0, width 4 -> simm16 = ((4-1)<<11)|(0<<6)|20 = 6164
__device__ inline int get_xcd() {
  return (int)(__builtin_amdgcn_s_getreg(6164) & 7u);
}

// -------- W pre-transpose into MFMA-B-frag order, fp32 -> bf16 --------
__global__ __launch_bounds__(256) void transpose_w(const float* __restrict__ w,
                                                   uint4* __restrict__ wt) {
  int c = blockIdx.x * 256 + threadIdx.x;  // 4096 chunks
  int l = c & 63;
  int kt = (c >> 6) & 7;
  int nt = c >> 9;
  int n = nt * 16 + (l & 15);
  int kb = kt * 32 + ((l >> 4) & 3) * 8;
  unsigned d[4];
#pragma unroll
  for (int j = 0; j < 4; ++j) {
    float a = w[(size_t)(kb + 2 * j) * OUT_F + n];
    float b = w[(size_t)(kb + 2 * j + 1) * OUT_F + n];
    d[j] = cvt2_bf16(a, b);
  }
  wt[c] = make_uint4(d[0], d[1], d[2], d[3]);
}

// -------- fused: even blocks = MFMA GEMM tile, odd blocks = dst histogram ----
// hist role: per-XCD private histogram copies + WORKGROUP-scope atomics.
// Lines of cnt[xcd] are only ever touched by one XCD, so TCC-local (no sc1)
// atomics are correct — 8 L2s' atomic units instead of the one memory-side
// coherent point that was the 20.5 atomics/ns wall.
__global__ __launch_bounds__(256) void gemm_hist(const float* __restrict__ x,
                                                 const uint4* __restrict__ wt,
                                                 unsigned short* __restrict__ sup,
                                                 const int* __restrict__ ei,
                                                 int* __restrict__ cnt,
                                                 int* __restrict__ rank,
                                                 int nedges, int nth) {
  __shared__ uint4 As[1024];  // 16 KB
  __shared__ uint4 Bs[1024];  // 16 KB
  const int gid = blockIdx.x;
  const int sub = gid >> 1;

  if (gid & 1) {
    // ---- hist role ----
    const int xcd = get_xcd();
    int* mycnt = cnt + (size_t)xcd * N_NODES;
    int t = sub * 256 + threadIdx.x;
    int d[EDGE_ILP], ok[EDGE_ILP];
#pragma unroll
    for (int j = 0; j < EDGE_ILP; ++j) {
      int e = t + j * nth;
      ok[j] = e < nedges;
      d[j] = ei[ok[j] ? e : 0];
    }
    int rk[EDGE_ILP];
#pragma unroll
    for (int j = 0; j < EDGE_ILP; ++j)
      rk[j] = ok[j] ? __hip_atomic_fetch_add(&mycnt[d[j]], 1, __ATOMIC_RELAXED,
                                             __HIP_MEMORY_SCOPE_WORKGROUP)
                    : 0;
#pragma unroll
    for (int j = 0; j < EDGE_ILP; ++j) {
      int e = t + j * nth;
      if (ok[j]) rank[e] = (xcd << 28) | rk[j];  // coalesced store
    }
    return;
  }

  // ---- gemm role: support(bf16) = X @ W, 128x128 tile ----
  const int t = threadIdx.x;
  const int lane = t & 63;
  const int wv = t >> 6;
  const int wm = wv >> 1, wn = wv & 1;
  const int row0 = sub * 128;

  f32x4 acc[4][4];
#pragma unroll
  for (int mi = 0; mi < 4; ++mi)
#pragma unroll
    for (int ni = 0; ni < 4; ++ni) acc[mi][ni] = (f32x4){0.f, 0.f, 0.f, 0.f};

  for (int it = 0; it < 4; ++it) {
    const int k0 = it * 64;
#pragma unroll
    for (int i = 0; i < 4; ++i) {
      int ci = i * 256 + t;
      int g = ci >> 6, l = ci & 63;
      int m = (g >> 1) * 16 + (l & 15);
      int k = k0 + (g & 1) * 32 + ((l >> 4) & 3) * 8;
      int row = row0 + m;
      if (row > N_NODES - 1) row = N_NODES - 1;
      const float* src = x + (size_t)row * IN_F + k;
      f32x4 v0 = *(const f32x4*)src;
      f32x4 v1 = *(const f32x4*)(src + 4);
      As[ci] = make_uint4(cvt2_bf16(v0.x, v0.y), cvt2_bf16(v0.z, v0.w),
                          cvt2_bf16(v1.x, v1.y), cvt2_bf16(v1.z, v1.w));
      Bs[ci] = wt[((g >> 1) * 8 + it * 2 + (g & 1)) * 64 + l];
    }
    __syncthreads();
#pragma unroll
    for (int ktl = 0; ktl < 2; ++ktl) {
      bf16x8 af[4], bfr[4];
#pragma unroll
      for (int mi = 0; mi < 4; ++mi)
        af[mi] = *(bf16x8*)&As[((wm * 4 + mi) * 2 + ktl) * 64 + lane];
#pragma unroll
      for (int ni = 0; ni < 4; ++ni)
        bfr[ni] = *(bf16x8*)&Bs[((wn * 4 + ni) * 2 + ktl) * 64 + lane];
#pragma unroll
      for (int mi = 0; mi < 4; ++mi)
#pragma unroll
        for (int ni = 0; ni < 4; ++ni)
          acc[mi][ni] = __builtin_amdgcn_mfma_f32_16x16x32_bf16(af[mi], bfr[ni],
                                                                acc[mi][ni], 0, 0, 0);
    }
    __syncthreads();
  }

  const int quad = lane >> 4, col = lane & 15;
#pragma unroll
  for (int mi = 0; mi < 4; ++mi) {
#pragma unroll
    for (int r = 0; r < 4; ++r) {
      int row = row0 + (wm * 4 + mi) * 16 + quad * 4 + r;
      if (row < N_NODES) {
#pragma unroll
        for (int ni = 0; ni < 4; ++ni)
          sup[(size_t)row * OUT_F + (wn * 4 + ni) * 16 + col] =
              cvt1_bf16(acc[mi][ni][r]);
      }
    }
  }
}

// -------- per-node: exclusive prefix across XCD copies, degree -> rowptr ----
__global__ __launch_bounds__(256) void xprefix(int* __restrict__ cnt,
                                               int* __restrict__ rowptr) {
  int d = blockIdx.x * 256 + threadIdx.x;
  if (d >= N_NODES) return;
  int run = 0;
#pragma unroll
  for (int xc = 0; xc < NXCD; ++xc) {
    int c = cnt[(size_t)xc * N_NODES + d];
    cnt[(size_t)xc * N_NODES + d] = run;  // exclusive prefix along xcd
    run += c;
  }
  rowptr[d + 1] = run;
  if (d == 0) rowptr[0] = 0;
}

// -------- standalone gemm (fallback path only) --------
__global__ __launch_bounds__(256) void gemm_mfma(const float* __restrict__ x,
                                                 const uint4* __restrict__ wt,
                                                 unsigned short* __restrict__ sup) {
  __shared__ uint4 As[1024];
  __shared__ uint4 Bs[1024];
  const int t = threadIdx.x;
  const int lane = t & 63;
  const int wv = t >> 6;
  const int wm = wv >> 1, wn = wv & 1;
  const int row0 = blockIdx.x * 128;

  f32x4 acc[4][4];
#pragma unroll
  for (int mi = 0; mi < 4; ++mi)
#pragma unroll
    for (int ni = 0; ni < 4; ++ni) acc[mi][ni] = (f32x4){0.f, 0.f, 0.f, 0.f};

  for (int it = 0; it < 4; ++it) {
    const int k0 = it * 64;
#pragma unroll
    for (int i = 0; i < 4; ++i) {
      int ci = i * 256 + t;
      int g = ci >> 6, l = ci & 63;
      int m = (g >> 1) * 16 + (l & 15);
      int k = k0 + (g & 1) * 32 + ((l >> 4) & 3) * 8;
      int row = row0 + m;
      if (row > N_NODES - 1) row = N_NODES - 1;
      const float* src = x + (size_t)row * IN_F + k;
      f32x4 v0 = *(const f32x4*)src;
      f32x4 v1 = *(const f32x4*)(src + 4);
      As[ci] = make_uint4(cvt2_bf16(v0.x, v0.y), cvt2_bf16(v0.z, v0.w),
                          cvt2_bf16(v1.x, v1.y), cvt2_bf16(v1.z, v1.w));
      Bs[ci] = wt[((g >> 1) * 8 + it * 2 + (g & 1)) * 64 + l];
    }
    __syncthreads();
#pragma unroll
    for (int ktl = 0; ktl < 2; ++ktl) {
      bf16x8 af[4], bfr[4];
#pragma unroll
      for (int mi = 0; mi < 4; ++mi)
        af[mi] = *(bf16x8*)&As[((wm * 4 + mi) * 2 + ktl) * 64 + lane];
#pragma unroll
      for (int ni = 0; ni < 4; ++ni)
        bfr[ni] = *(bf16x8*)&Bs[((wn * 4 + ni) * 2 + ktl) * 64 + lane];
#pragma unroll
      for (int mi = 0; mi < 4; ++mi)
#pragma unroll
        for (int ni = 0; ni < 4; ++ni)
          acc[mi][ni] = __builtin_amdgcn_mfma_f32_16x16x32_bf16(af[mi], bfr[ni],
                                                                acc[mi][ni], 0, 0, 0);
    }
    __syncthreads();
  }

  const int quad = lane >> 4, col = lane & 15;
#pragma unroll
  for (int mi = 0; mi < 4; ++mi) {
#pragma unroll
    for (int r = 0; r < 4; ++r) {
      int row = row0 + (wm * 4 + mi) * 16 + quad * 4 + r;
      if (row < N_NODES) {
#pragma unroll
        for (int ni = 0; ni < 4; ++ni)
          sup[(size_t)row * OUT_F + (wn * 4 + ni) * 16 + col] =
              cvt1_bf16(acc[mi][ni][r]);
      }
    }
  }
}

// -------- in-place inclusive scan, 1024 elems / block --------
__global__ __launch_bounds__(256) void scan1(int* __restrict__ a,
                                             int* __restrict__ bsum, int n) {
  __shared__ int s[256];
  const int t = threadIdx.x;
  const int base = blockIdx.x * SCAN_ELEMS + t * 4;
  int v0 = (base + 0 < n) ? a[base + 0] : 0;
  int v1 = (base + 1 < n) ? a[base + 1] : 0;
  int v2 = (base + 2 < n) ? a[base + 2] : 0;
  int v3 = (base + 3 < n) ? a[base + 3] : 0;
  v1 += v0; v2 += v1; v3 += v2;
  s[t] = v3;
  __syncthreads();
  for (int off = 1; off < 256; off <<= 1) {
    int x = (t >= off) ? s[t - off] : 0;
    __syncthreads();
    s[t] += x;
    __syncthreads();
  }
  int excl = (t == 0) ? 0 : s[t - 1];
  if (base + 0 < n) a[base + 0] = v0 + excl;
  if (base + 1 < n) a[base + 1] = v1 + excl;
  if (base + 2 < n) a[base + 2] = v2 + excl;
  if (base + 3 < n) a[base + 3] = v3 + excl;
  if (t == 255 && bsum) bsum[blockIdx.x] = s[255];
}

// scan fixup + fold final row starts into the per-XCD base arrays:
// cnt[x][d] = rowptr[d] + (exclusive prefix of per-XCD counts) = absolute base
__global__ __launch_bounds__(256) void scan3b(int* __restrict__ a,
                                              const int* __restrict__ bsum,
                                              int* __restrict__ cnt, int n) {
  int b = blockIdx.x;
  int add = (b == 0) ? 0 : bsum[b - 1];
  int i = b * SCAN_ELEMS + threadIdx.x * 4;
#pragma unroll
  for (int j = 0; j < 4; ++j) {
    int idx = i + j;
    if (idx < n) {
      int v = a[idx] + add;
      a[idx] = v;
      if (idx < N_NODES) {
#pragma unroll
        for (int xc = 0; xc < NXCD; ++xc)
          cnt[(size_t)xc * N_NODES + idx] += v;
      }
    }
  }
}

// -------- scatter edges into CSR slots — NO atomics (rank precomputed) ----
__global__ __launch_bounds__(256) void build_scatter(const int* __restrict__ ei,
                                                     const float* __restrict__ ew,
                                                     const int* __restrict__ cnt,
                                                     const int* __restrict__ rank,
                                                     int2* __restrict__ edges,
                                                     int nedges, int nth) {
  int t = blockIdx.x * 256 + threadIdx.x;
  int d[EDGE_ILP], s[EDGE_ILP], ok[EDGE_ILP];
  unsigned rk[EDGE_ILP];
  float wvl[EDGE_ILP];
#pragma unroll
  for (int j = 0; j < EDGE_ILP; ++j) {
    int e = t + j * nth;
    ok[j] = e < nedges;
    int ee = ok[j] ? e : 0;
    d[j] = ei[ee];
    s[j] = ei[nedges + ee];
    wvl[j] = ew[ee];
    rk[j] = (unsigned)rank[ee];
  }
#pragma unroll
  for (int j = 0; j < EDGE_ILP; ++j) {
    if (ok[j]) {
      int xc = rk[j] >> 28;
      int r = rk[j] & 0x0fffffff;
      int pos = cnt[(size_t)xc * N_NODES + d[j]] + r;
      edges[pos] = make_int2(s[j], __float_as_int(wvl[j]));
    }
  }
}

// -------- aggregate: one wave per dst, bf16 support gather, no atomics --------
__global__ __launch_bounds__(256) void aggregate_bf16(const int* __restrict__ rowptr,
                                                      const int2* __restrict__ edges,
                                                      const unsigned short* __restrict__ sup,
                                                      float* __restrict__ out, int nnodes) {
  int wave = (int)((blockIdx.x * 256u + threadIdx.x) >> 6);
  int lane = threadIdx.x & 63;
  if (wave >= nnodes) return;
  int beg = rowptr[wave];
  int end = rowptr[wave + 1];
  float2 acc = make_float2(0.f, 0.f);
  int e = beg;
  for (; e + 4 <= end; e += 4) {
    int2 m0 = edges[e + 0];
    int2 m1 = edges[e + 1];
    int2 m2 = edges[e + 2];
    int2 m3 = edges[e + 3];
    unsigned u0 = *(const unsigned*)(sup + (size_t)m0.x * OUT_F + lane * 2);
    unsigned u1 = *(const unsigned*)(sup + (size_t)m1.x * OUT_F + lane * 2);
    unsigned u2 = *(const unsigned*)(sup + (size_t)m2.x * OUT_F + lane * 2);
    unsigned u3 = *(const unsigned*)(sup + (size_t)m3.x * OUT_F + lane * 2);
    float w0 = __int_as_float(m0.y), w1 = __int_as_float(m1.y);
    float w2 = __int_as_float(m2.y), w3 = __int_as_float(m3.y);
    acc.x = fmaf(__uint_as_float(u0 << 16), w0, acc.x);
    acc.y = fmaf(__uint_as_float(u0 & 0xffff0000u), w0, acc.y);
    acc.x = fmaf(__uint_as_float(u1 << 16), w1, acc.x);
    acc.y = fmaf(__uint_as_float(u1 & 0xffff0000u), w1, acc.y);
    acc.x = fmaf(__uint_as_float(u2 << 16), w2, acc.x);
    acc.y = fmaf(__uint_as_float(u2 & 0xffff0000u), w2, acc.y);
    acc.x = fmaf(__uint_as_float(u3 << 16), w3, acc.x);
    acc.y = fmaf(__uint_as_float(u3 & 0xffff0000u), w3, acc.y);
  }
  for (; e < end; ++e) {
    int2 m = edges[e];
    unsigned u = *(const unsigned*)(sup + (size_t)m.x * OUT_F + lane * 2);
    float w = __int_as_float(m.y);
    acc.x = fmaf(__uint_as_float(u << 16), w, acc.x);
    acc.y = fmaf(__uint_as_float(u & 0xffff0000u), w, acc.y);
  }
  *(float2*)(out + (size_t)wave * OUT_F + lane * 2) = acc;
}

// -------- fallback: atomic scatter (only if ws too small) --------
__global__ __launch_bounds__(256) void scatter_edges(const int* __restrict__ ei,
                                                     const float* __restrict__ ew,
                                                     const unsigned short* __restrict__ sup,
                                                     float* __restrict__ out, int nedges) {
  int gwave = (int)((blockIdx.x * 256u + threadIdx.x) >> 6);
  int lane = threadIdx.x & 63;
  if (gwave >= nedges) return;
  int dst = ei[gwave];
  int src = ei[nedges + gwave];
  float wgt = ew[gwave];
  unsigned u = *(const unsigned*)(sup + (size_t)src * OUT_F + lane * 2);
  float* op = out + (size_t)dst * OUT_F + lane * 2;
  atomicAdd(op, __uint_as_float(u << 16) * wgt);
  atomicAdd(op + 1, __uint_as_float(u & 0xffff0000u) * wgt);
}

extern "C" void kernel_launch(void* const* d_in, const int* in_sizes, int n_in,
                              void* d_out, int out_size, void* d_ws, size_t ws_size,
                              hipStream_t stream) {
  const float* x = (const float*)d_in[0];
  const int* ei = (const int*)d_in[1];      // [2, E] int32 flat: row0=dst, row1=src
  const float* ew = (const float*)d_in[2];  // [E]
  const float* w = (const float*)d_in[3];   // [256,128]
  float* out = (float*)d_out;
  const int nedges = in_sizes[2];

  // workspace layout (bytes)
  const size_t off_support = 0;
  const size_t sz_support = (size_t)N_NODES * OUT_F * 2;  // 25,600,000 (bf16)
  const size_t off_rowptr = off_support + sz_support;     // 25,600,000
  const size_t sz_rowptr = (size_t)(N_NODES + 1) * 4;     // 400,004 -> pad 400,008
  const size_t off_bsum = off_rowptr + 400008;            // 26,000,008
  const size_t off_wt = off_bsum + 408;                   // 26,000,416 (16-aligned)
  const size_t sz_wt = 4096 * 16;                         // 65,536
  const size_t off_rank = off_wt + sz_wt;                 // 26,065,952
  const size_t off_cnt = off_rank + (size_t)nedges * 4;   // 32,465,952
  const size_t sz_cnt = (size_t)NXCD * N_NODES * 4;       // 3,200,000
  const size_t off_edges = off_cnt + sz_cnt;              // 35,665,952
  const size_t total_ws = off_edges + (size_t)nedges * 8; // 48,465,952

  unsigned short* support = (unsigned short*)((char*)d_ws + off_support);
  int* rowptr = (int*)((char*)d_ws + off_rowptr);
  int* bsum = (int*)((char*)d_ws + off_bsum);
  uint4* wt = (uint4*)((char*)d_ws + off_wt);
  int* rank = (int*)((char*)d_ws + off_rank);
  int* cnt = (int*)((char*)d_ws + off_cnt);
  int2* edges = (int2*)((char*)d_ws + off_edges);

  transpose_w<<<16, 256, 0, stream>>>(w, wt);

  if (ws_size < total_ws) {
    const int gblocks = (N_NODES + 127) / 128;
    gemm_mfma<<<gblocks, 256, 0, stream>>>(x, wt, support);
    hipMemsetAsync(d_out, 0, (size_t)out_size * sizeof(float), stream);
    int sblocks = (nedges + 3) / 4;
    scatter_edges<<<sblocks, 256, 0, stream>>>(ei, ew, support, out, nedges);
    return;
  }

  const int n1 = N_NODES + 1;
  const int nb = (n1 + SCAN_ELEMS - 1) / SCAN_ELEMS;    // 98
  const int eblocks = (nedges / EDGE_ILP + 255) / 256;  // 782
  const int nth = eblocks * 256;                        // 200192
  const int gblocks = (N_NODES + 127) / 128;            // 782

  hipMemsetAsync(cnt, 0, sz_cnt, stream);
  // fused: even blocks gemm (782), odd blocks hist (782)
  gemm_hist<<<gblocks + eblocks, 256, 0, stream>>>(x, wt, support, ei, cnt,
                                                   rank, nedges, nth);
  xprefix<<<(N_NODES + 255) / 256, 256, 0, stream>>>(cnt, rowptr);
  scan1<<<nb, 256, 0, stream>>>(rowptr, bsum, n1);
  scan1<<<1, 256, 0, stream>>>(bsum, (int*)nullptr, nb);
  scan3b<<<nb, 256, 0, stream>>>(rowptr, bsum, cnt, n1);
  build_scatter<<<eblocks, 256, 0, stream>>>(ei, ew, cnt, rank, edges, nedges, nth);

  const int ablocks = (N_NODES + 3) / 4;
  aggregate_bf16<<<ablocks, 256, 0, stream>>>(rowptr, edges, support, out, N_NODES);
}